// Round 8
// baseline (384.090 us; speedup 1.0000x reference)
//
#include <hip/hip_runtime.h>
#include <cstdint>
#include <cstddef>

#define TT 512
#define BB 128
#define EE 128
#define SS 1024
#define NEG_INF (-1e30f)

typedef _Float16 half8 __attribute__((ext_vector_type(8)));
typedef float floatx4 __attribute__((ext_vector_type(4)));

// ---------- fp16 helpers ----------
__device__ __forceinline__ unsigned int pkh(float x, float y) {
    _Float16 hx = (_Float16)x, hy = (_Float16)y;
    unsigned short bx, by;
    __builtin_memcpy(&bx, &hx, 2); __builtin_memcpy(&by, &hy, 2);
    return (unsigned int)bx | ((unsigned int)by << 16);
}

// ============================================================
// prefixF: per-b prefix sums + range-max precompute.
// Adds CSb (b-major chunk-suffix max) for the new phaseC.
// ============================================================
__global__ __launch_bounds__(64) void prefixF(
    const float* __restrict__ d1, const float* __restrict__ d2,
    const float* __restrict__ u,
    float* __restrict__ F, float* __restrict__ Bv,
    float* __restrict__ d2T, float* __restrict__ FT,
    float* __restrict__ BvT, float* __restrict__ CST,
    float* __restrict__ CMT, float* __restrict__ HT,
    float* __restrict__ CSb)
{
    const int b = blockIdx.x;
    const int lane = threadIdx.x;
    const int t0 = lane * 8;

    float l1[8], l2[8], g[8];
#pragma unroll
    for (int j = 0; j < 8; ++j) {
        const int t = t0 + j;
        l1[j] = d1[t * BB + b];
        l2[j] = d2[t * BB + b];
        g[j] = u[t * BB + b] - l1[j] - l2[j];
    }
    float p[8], s = 0.f;
#pragma unroll
    for (int j = 0; j < 8; ++j) { s += g[j]; p[j] = s; }

    float v = s;
#pragma unroll
    for (int off = 1; off < 64; off <<= 1) {
        float o = __shfl_up(v, off);
        if (lane >= off) v += o;
    }
    const float excl = v - s;

    float Fv[8];
#pragma unroll
    for (int j = 0; j < 8; ++j) Fv[j] = excl + p[j];

#pragma unroll
    for (int j = 0; j < 8; ++j) {
        const int t = t0 + j;
        const float Fm1 = (j > 0) ? Fv[j - 1] : excl;
        const float Bvv = Fm1 - l1[j];
        F  [b * TT + t] = Fv[j];
        Bv [b * TT + t] = Bvv;
        d2T[b * TT + t] = l2[j];
        FT [t * BB + b] = Fv[j];
        BvT[t * BB + b] = Bvv;
    }

    // ---- range-max structures (chunk = 32 t = 4 lanes) ----
    float pm[8], sm[8];
    pm[0] = Fv[0];
#pragma unroll
    for (int j = 1; j < 8; ++j) pm[j] = fmaxf(pm[j - 1], Fv[j]);
    sm[7] = Fv[7];
#pragma unroll
    for (int j = 6; j >= 0; --j) sm[j] = fmaxf(sm[j + 1], Fv[j]);

    float pcar = NEG_INF, scar = NEG_INF;
#pragma unroll
    for (int off = 1; off <= 3; ++off) {
        float xu = __shfl_up(pm[7], off);
        if ((lane & 3) >= off) pcar = fmaxf(pcar, xu);
        float xd = __shfl_down(sm[0], off);
        if ((lane & 3) + off <= 3) scar = fmaxf(scar, xd);
    }

#pragma unroll
    for (int j = 0; j < 8; ++j) {
        const int t = t0 + j;
        const float Hv  = fmaxf(pcar, (j > 0) ? pm[j - 1] : NEG_INF);
        const float CSv = fmaxf(sm[j], scar);
        HT [t * BB + b] = Hv;
        CST[t * BB + b] = CSv;
        CSb[b * TT + t] = CSv;          // b-major for phaseC
    }
    if ((lane & 3) == 0)
        CMT[(lane >> 2) * BB + b] = fmaxf(sm[0], scar);
}

// ============================================================
// calcM2 (original — measured ~11 us)
// ============================================================
__global__ __launch_bounds__(256) void calcM2(
    const float* __restrict__ FT, const float* __restrict__ BvT,
    const float* __restrict__ CST, const float* __restrict__ CMT,
    const float* __restrict__ HT, const float* __restrict__ u,
    float* __restrict__ m)
{
    const int t = (int)blockIdx.y;
    const int ci = (int)blockIdx.x;
    const int ct = t >> 5;
    if (ci > ct) return;

    const int tid = threadIdx.x;
    const int b = tid & 127, h = tid >> 7;
    const int ib = 32 * ci;

    __shared__ float cand[BB][66];
    __shared__ float Tot[2][BB];
    __shared__ float red[4][64];

    const float Ft = FT[t * BB + b];

    if (ci < ct) {
        float K = HT[t * BB + b];
        for (int c = ci + 1; c < ct; ++c) K = fmaxf(K, CMT[c * BB + b]);
#pragma unroll
        for (int j = 0; j < 16; ++j) {
            const int jj = 16 * h + j;
            const int i = ib + jj;
            const float R = fmaxf(CST[i * BB + b], K);
            const float Bvv = BvT[i * BB + b];
            cand[b][2 * jj]     = Ft - fmaxf(Bvv, R);
            cand[b][2 * jj + 1] = Ft - R;
        }
    } else {
        float vv[16], sfx[16];
#pragma unroll
        for (int j = 0; j < 16; ++j) {
            const int i = ib + 16 * h + j;
            vv[j] = (i < t) ? FT[i * BB + b] : NEG_INF;
        }
        sfx[15] = vv[15];
#pragma unroll
        for (int j = 14; j >= 0; --j) sfx[j] = fmaxf(vv[j], sfx[j + 1]);
        Tot[h][b] = sfx[0];
        __syncthreads();
        const float carry = (h == 0) ? Tot[1][b] : NEG_INF;
        const float ub = u[t * BB + b];
#pragma unroll
        for (int j = 0; j < 16; ++j) {
            const int jj = 16 * h + j;
            const int i = ib + jj;
            const float R = fmaxf(sfx[j], carry);
            const float Bvv = BvT[i * BB + b];
            cand[b][2 * jj]     = Ft - fmaxf(Bvv, R);
            cand[b][2 * jj + 1] = (i == t) ? ub : (Ft - R);
        }
    }
    __syncthreads();

    {
        const int s = tid & 63, g = tid >> 6;
        float mx = NEG_INF;
        const int b0 = g * 32;
#pragma unroll 8
        for (int bb = b0; bb < b0 + 32; ++bb) mx = fmaxf(mx, cand[bb][s]);
        red[g][s] = mx;
    }
    __syncthreads();
    if (tid < 64) {
        const float r = fmaxf(fmaxf(red[0][tid], red[1][tid]),
                              fmaxf(red[2][tid], red[3][tid]));
        const int s_glob = 64 * ci + tid;
        if (s_glob < 2 * t + 2) m[(size_t)t * SS + s_glob] = r;
    }
}

// ============================================================
// phaseC_mfma — Round-8: 5 blocks/CU residency.
//  - LDS diet: only Ws+Vt (+ TP/FT0/SCM tables) stay -> 28.2 KB
//    (was 34.8).  Ai/Bi/CS/d2 are per-chunk coalesced GLOBAL
//    prefetches from b-major arrays; S0 tree-scan prologue
//    replaced by S0i = fmax(CSb[i], SCM[ck+1]) (exact fmax
//    composition -> bit-identical).
//  - __launch_bounds__(256,5) caps VGPR so 20 waves/CU fit.
//  - pack-V-first ordering shrinks register peak (pv dies before
//    W-compute).
//  - keeps: R7 12-block/b split grid + atomic epilogue, pitch-72,
//    incremental range-max, 1-deep prefetch, setprio on MFMA.
// ============================================================
#define PWH 72                 // row pitch in halfwords (16B-aligned rows)
#define PWW 36                 // row pitch in words
#define VTO 2304               // Ws = 64*36 words
#define TPO 6912               // Vt ends at 2304+4608=6912
#define FT0O 6976
#define SCMO 7040
// total 7056 words = 28224 B -> 5 blocks/CU

__global__ __launch_bounds__(256, 5) void phaseC_mfma(
    const float* __restrict__ F, const float* __restrict__ Bvg,
    const float* __restrict__ d2T, const float* __restrict__ CSb,
    const float* __restrict__ CMT, const float* __restrict__ m,
    const float* __restrict__ v1, const float* __restrict__ v2,
    float* __restrict__ out)
{
    const int b  = blockIdx.x & (BB - 1);
    const int wk = blockIdx.x >> 7;

    // work table: wk 0..5 : 8-chunk blocks (7,0)(7,8)(6,0)(5,0)(4,0)(3,0)
    //             wk 6..11: (6,8,6)(2,0,6)(5,8,4)(1,0,4)(4,8,2)(0,0,2)
    int tt, ck0, nck;
    if (wk < 6) {
        nck = 8;
        ck0 = (wk == 1) ? 8 : 0;
        tt  = (wk <= 1) ? 7 : 8 - wk;
    } else {
        const int j = wk - 6;
        nck = 6 - 2 * (j >> 1);
        if (j & 1) { tt = 2 - (j >> 1); ck0 = 0; }
        else       { tt = 6 - (j >> 1); ck0 = 8; }
    }
    const int t0 = tt * 64;
    const int t0c = t0 >> 5;               // # strictly-below chunks
    const int ckEnd = ck0 + nck;
    const bool splitTile = (tt >= 4);      // 2 writers -> atomicAdd

    const int tid = threadIdx.x;

    __shared__ float sh[7056];

    const int lane = tid & 63, w = tid >> 6;
    const int wr = w >> 1, wc = w & 1;            // 2x2 wave grid
    const int n = lane & 15;
    const int kq = (lane >> 4) * 8;
    const int il = tid & 31, g = tid >> 5;        // W staging
    const int veb = tid & 7;                      // V staging: e quad
    const int vip = ((tid >> 3) & 7) + 8 * wc;    // i-pair 0..15
    const int veh = wr * 64;                      // e half

    // ---------- pipeline registers ----------
    float4 pv[8];
    float2 pmv[8];
    float pAi, pBi, pAux;   // F[i-1], Bv[i], (below? CSb[i] : d2T[i])

    auto prefetch = [&](int ck) {
        const int i = 32 * ck + il;
#pragma unroll
        for (int r8 = 0; r8 < 8; ++r8) {
            const int t = t0 + 8 * g + r8;
            pmv[r8] = *(const float2*)&m[(size_t)t * SS + 2 * i];
        }
        pAi  = F  [b * TT + ((i > 0) ? i - 1 : 0)];
        pBi  = Bvg[b * TT + i];
        pAux = (32 * ck < t0) ? CSb[b * TT + i] : d2T[b * TT + i];
        const int i0 = 32 * ck + 2 * vip, i1 = i0 + 1;
        const float* p10 = v1 + ((size_t)i0 * BB + b) * EE;
        const float* p11 = v1 + ((size_t)i1 * BB + b) * EE;
        const float* p20 = v2 + ((size_t)i0 * BB + b) * EE;
        const float* p21 = v2 + ((size_t)i1 * BB + b) * EE;
#pragma unroll
        for (int c = 0; c < 2; ++c) {
            const int e0 = 4 * veb + 32 * c + veh;
            pv[4 * c + 0] = *(const float4*)&p10[e0];
            pv[4 * c + 1] = *(const float4*)&p11[e0];
            pv[4 * c + 2] = *(const float4*)&p20[e0];
            pv[4 * c + 3] = *(const float4*)&p21[e0];
        }
    };

    // ---------- prologue: FT0 + TP (wave 0), SCM (wave 1) ----------
    if (tid < 64) {
        float xi = F[b * TT + t0 + tid];
        sh[FT0O + tid] = xi;
        float sc = xi;
#pragma unroll
        for (int off = 1; off < 64; off <<= 1) {
            const float y = __shfl_up(sc, off);
            if (tid >= off) sc = fmaxf(sc, y);
        }
        const float ex = __shfl_up(sc, 1);
        sh[TPO + tid] = (tid == 0) ? NEG_INF : ex;
    } else if (tid < 128) {
        const int c = tid - 64;
        float cm = (c < t0c) ? CMT[c * BB + b] : NEG_INF;
#pragma unroll
        for (int off = 1; off < 16; off <<= 1) {
            const float y = __shfl_down(cm, off);
            cm = fmaxf(cm, (c + off < 16) ? y : NEG_INF);
        }
        if (c < 16) sh[SCMO + c] = cm;
    }

    prefetch(ck0);          // hide chunk-0 loads under prologue/barrier

    __syncthreads();

    float Freg2[8];
#pragma unroll
    for (int j = 0; j < 8; ++j) Freg2[j] = sh[FT0O + 8 * g + j];
    const float qstart = sh[TPO + 8 * g];

    floatx4 acc[2][4];
#pragma unroll
    for (int r = 0; r < 2; ++r)
#pragma unroll
        for (int j = 0; j < 4; ++j) acc[r][j] = (floatx4)0.f;

    for (int ck = ck0; ck < ckEnd; ++ck) {
        const int ib = 32 * ck;
        const int i = ib + il;
        const bool below = (ib < t0);          // block-uniform per chunk

        // ---- pack V fp16 first (pv dies -> lower reg peak) ----
        uint2 vreg[8];
#pragma unroll
        for (int c = 0; c < 2; ++c) {
            const float4 xa = pv[4 * c + 0], xb = pv[4 * c + 1];
            const float4 ya = pv[4 * c + 2], yb = pv[4 * c + 3];
            vreg[4 * c + 0] = make_uint2(pkh(xa.x, ya.x), pkh(xb.x, yb.x));
            vreg[4 * c + 1] = make_uint2(pkh(xa.y, ya.y), pkh(xb.y, yb.y));
            vreg[4 * c + 2] = make_uint2(pkh(xa.z, ya.z), pkh(xb.z, yb.z));
            vreg[4 * c + 3] = make_uint2(pkh(xa.w, ya.w), pkh(xb.w, yb.w));
        }

        // ---- W closed form + min(m) -> registers ----
        unsigned int wreg[8];
        {
            const float Ai = (i > 0) ? pAi : 0.f;
            const float Bi = pBi;
            const int li = i - t0;
            float q, S0i = 0.f;
            if (below) {
                S0i = fmaxf(pAux, sh[SCMO + ck + 1]);
                q = qstart;
            } else {
                q = NEG_INF;
                for (int k = li; k < 8 * g; ++k)
                    q = fmaxf(q, sh[FT0O + k]);
            }
#pragma unroll
            for (int r8 = 0; r8 < 8; ++r8) {
                const int t_l = 8 * g + r8;
                const float2 mv = pmv[r8];
                float w0 = 0.f, w1 = 0.f;
                if (below) {
                    const float R = fmaxf(S0i, q);
                    const float a0 = fmaxf(Ai, R) - fmaxf(Bi, R);
                    const float a1 = fmaxf(Bi - R, 0.f);
                    w0 = fminf(a0, mv.x);
                    w1 = fminf(a1, mv.y);
                    q = fmaxf(q, Freg2[r8]);
                } else {
                    if (li <= t_l) {
                        const float R = q;
                        const float a0 = fmaxf(Ai, R) - fmaxf(Bi, R);
                        const float a1 = (li == t_l) ? pAux
                                                     : fmaxf(Bi - R, 0.f);
                        w0 = fminf(a0, mv.x);
                        w1 = fminf(a1, mv.y);
                    }
                    q = fmaxf(q, (t_l >= li) ? Freg2[r8] : NEG_INF);
                }
                wreg[r8] = pkh(w0, w1);
            }
        }

        __syncthreads();                 // MFMA(prev) done reading LDS

        // ---- raw LDS writes only between the barriers ----
#pragma unroll
        for (int r8 = 0; r8 < 8; ++r8)
            ((unsigned int*)sh)[(8 * g + r8) * PWW + il] = wreg[r8];
        {
            unsigned int* vt = (unsigned int*)sh + VTO;
            const int dw = 2 * vip;
#pragma unroll
            for (int c = 0; c < 2; ++c) {
                const int e0 = 4 * veb + 32 * c + veh;
                *(uint2*)&vt[(e0 + 0) * PWW + dw] = vreg[4 * c + 0];
                *(uint2*)&vt[(e0 + 1) * PWW + dw] = vreg[4 * c + 1];
                *(uint2*)&vt[(e0 + 2) * PWW + dw] = vreg[4 * c + 2];
                *(uint2*)&vt[(e0 + 3) * PWW + dw] = vreg[4 * c + 3];
            }
        }

        __syncthreads();                 // staging visible

        // ---- issue NEXT chunk's global loads; latency under MFMA
        if (ck + 1 < ckEnd) prefetch(ck + 1);

        // ---- MFMA: 2 k-steps x (2 t-rows x 4 e-tiles) per wave ----
        __builtin_amdgcn_s_setprio(1);
        {
            const _Float16* WsH = (const _Float16*)sh;
            const _Float16* VtH = (const _Float16*)(sh + VTO);
#pragma unroll
            for (int k2 = 0; k2 < 64; k2 += 32) {
                const half8 av0 = *(const half8*)&WsH[(32 * wr + n) * PWH + kq + k2];
                const half8 av1 = *(const half8*)&WsH[(32 * wr + 16 + n) * PWH + kq + k2];
#pragma unroll
                for (int j = 0; j < 4; ++j) {
                    const half8 bv = *(const half8*)&VtH[(64 * wc + 16 * j + n) * PWH + kq + k2];
                    acc[0][j] = __builtin_amdgcn_mfma_f32_16x16x32_f16(av0, bv, acc[0][j], 0, 0, 0);
                    acc[1][j] = __builtin_amdgcn_mfma_f32_16x16x32_f16(av1, bv, acc[1][j], 0, 0, 0);
                }
            }
        }
        __builtin_amdgcn_s_setprio(0);
    }

    // ---- epilogue: store (single writer) or atomicAdd (split) ----
    {
        const int q = lane >> 4;
#pragma unroll
        for (int r = 0; r < 2; ++r) {
#pragma unroll
            for (int j = 0; j < 4; ++j) {
#pragma unroll
                for (int reg = 0; reg < 4; ++reg) {
                    const int t = t0 + 32 * wr + 16 * r + 4 * q + reg;
                    const int col = 64 * wc + 16 * j + n;
                    float* dst = &out[((size_t)t * BB + b) * EE + col];
                    if (splitTile) atomicAdd(dst, acc[r][j][reg]);
                    else           *dst = acc[r][j][reg];
                }
            }
        }
    }
}

// ============================================================
extern "C" void kernel_launch(void* const* d_in, const int* in_sizes, int n_in,
                              void* d_out, int out_size, void* d_ws, size_t ws_size,
                              hipStream_t stream) {
    const float* v1 = (const float*)d_in[0];
    const float* v2 = (const float*)d_in[1];
    const float* d1 = (const float*)d_in[2];
    const float* d2 = (const float*)d_in[3];
    const float* u  = (const float*)d_in[4];
    float* out = (float*)d_out;

    char* ws = (char*)d_ws;
    float* m   = (float*)ws;                                   // 2 MB
    float* F   = m   + (size_t)TT * SS;
    float* Bvp = F   + (size_t)BB * TT;
    float* d2T = Bvp + (size_t)BB * TT;
    float* FT  = d2T + (size_t)BB * TT;
    float* BvT = FT  + (size_t)BB * TT;
    float* CST = BvT + (size_t)BB * TT;
    float* HT  = CST + (size_t)BB * TT;
    float* CMT = HT  + (size_t)BB * TT;                        // 16*128
    float* CSb = CMT + (size_t)16 * BB;

    // zero the atomic-accumulated region (t >= 256) of out
    hipMemsetAsync(out + (size_t)256 * BB * EE, 0,
                   (size_t)256 * BB * EE * sizeof(float), stream);

    prefixF<<<dim3(BB), dim3(64), 0, stream>>>(d1, d2, u, F, Bvp, d2T, FT,
                                               BvT, CST, CMT, HT, CSb);
    calcM2 <<<dim3(16, TT), dim3(256), 0, stream>>>(FT, BvT, CST, CMT, HT, u, m);
    phaseC_mfma<<<dim3(12 * BB), dim3(256), 0, stream>>>(F, Bvp, d2T, CSb, CMT,
                                                         m, v1, v2, out);
}

// Round 9
// 206.461 us; speedup vs baseline: 1.8604x; 1.8604x over previous
//
#include <hip/hip_runtime.h>
#include <cstdint>
#include <cstddef>

#define TT 512
#define BB 128
#define EE 128
#define SS 1024
#define NEG_INF (-1e30f)

typedef _Float16 half8 __attribute__((ext_vector_type(8)));
typedef float floatx4 __attribute__((ext_vector_type(4)));

// ---------- fp16 helpers ----------
__device__ __forceinline__ unsigned int pkh(float x, float y) {
    _Float16 hx = (_Float16)x, hy = (_Float16)y;
    unsigned short bx, by;
    __builtin_memcpy(&bx, &hx, 2); __builtin_memcpy(&by, &hy, 2);
    return (unsigned int)bx | ((unsigned int)by << 16);
}

// ============================================================
// prefixF: per-b prefix sums + range-max precompute.
// ============================================================
__global__ __launch_bounds__(64) void prefixF(
    const float* __restrict__ d1, const float* __restrict__ d2,
    const float* __restrict__ u,
    float* __restrict__ F, float* __restrict__ Bv,
    float* __restrict__ d2T, float* __restrict__ FT,
    float* __restrict__ BvT, float* __restrict__ CST,
    float* __restrict__ CMT, float* __restrict__ HT,
    float* __restrict__ CSb)
{
    const int b = blockIdx.x;
    const int lane = threadIdx.x;
    const int t0 = lane * 8;

    float l1[8], l2[8], g[8];
#pragma unroll
    for (int j = 0; j < 8; ++j) {
        const int t = t0 + j;
        l1[j] = d1[t * BB + b];
        l2[j] = d2[t * BB + b];
        g[j] = u[t * BB + b] - l1[j] - l2[j];
    }
    float p[8], s = 0.f;
#pragma unroll
    for (int j = 0; j < 8; ++j) { s += g[j]; p[j] = s; }

    float v = s;
#pragma unroll
    for (int off = 1; off < 64; off <<= 1) {
        float o = __shfl_up(v, off);
        if (lane >= off) v += o;
    }
    const float excl = v - s;

    float Fv[8];
#pragma unroll
    for (int j = 0; j < 8; ++j) Fv[j] = excl + p[j];

#pragma unroll
    for (int j = 0; j < 8; ++j) {
        const int t = t0 + j;
        const float Fm1 = (j > 0) ? Fv[j - 1] : excl;
        const float Bvv = Fm1 - l1[j];
        F  [b * TT + t] = Fv[j];
        Bv [b * TT + t] = Bvv;
        d2T[b * TT + t] = l2[j];
        FT [t * BB + b] = Fv[j];
        BvT[t * BB + b] = Bvv;
    }

    // ---- range-max structures (chunk = 32 t = 4 lanes) ----
    float pm[8], sm[8];
    pm[0] = Fv[0];
#pragma unroll
    for (int j = 1; j < 8; ++j) pm[j] = fmaxf(pm[j - 1], Fv[j]);
    sm[7] = Fv[7];
#pragma unroll
    for (int j = 6; j >= 0; --j) sm[j] = fmaxf(sm[j + 1], Fv[j]);

    float pcar = NEG_INF, scar = NEG_INF;
#pragma unroll
    for (int off = 1; off <= 3; ++off) {
        float xu = __shfl_up(pm[7], off);
        if ((lane & 3) >= off) pcar = fmaxf(pcar, xu);
        float xd = __shfl_down(sm[0], off);
        if ((lane & 3) + off <= 3) scar = fmaxf(scar, xd);
    }

#pragma unroll
    for (int j = 0; j < 8; ++j) {
        const int t = t0 + j;
        const float Hv  = fmaxf(pcar, (j > 0) ? pm[j - 1] : NEG_INF);
        const float CSv = fmaxf(sm[j], scar);
        HT [t * BB + b] = Hv;
        CST[t * BB + b] = CSv;
        CSb[b * TT + t] = CSv;          // b-major for phaseC
    }
    if ((lane & 3) == 0)
        CMT[(lane >> 2) * BB + b] = fmaxf(sm[0], scar);
}

// ============================================================
// calcM2 (original — unchanged)
// ============================================================
__global__ __launch_bounds__(256) void calcM2(
    const float* __restrict__ FT, const float* __restrict__ BvT,
    const float* __restrict__ CST, const float* __restrict__ CMT,
    const float* __restrict__ HT, const float* __restrict__ u,
    float* __restrict__ m)
{
    const int t = (int)blockIdx.y;
    const int ci = (int)blockIdx.x;
    const int ct = t >> 5;
    if (ci > ct) return;

    const int tid = threadIdx.x;
    const int b = tid & 127, h = tid >> 7;
    const int ib = 32 * ci;

    __shared__ float cand[BB][66];
    __shared__ float Tot[2][BB];
    __shared__ float red[4][64];

    const float Ft = FT[t * BB + b];

    if (ci < ct) {
        float K = HT[t * BB + b];
        for (int c = ci + 1; c < ct; ++c) K = fmaxf(K, CMT[c * BB + b]);
#pragma unroll
        for (int j = 0; j < 16; ++j) {
            const int jj = 16 * h + j;
            const int i = ib + jj;
            const float R = fmaxf(CST[i * BB + b], K);
            const float Bvv = BvT[i * BB + b];
            cand[b][2 * jj]     = Ft - fmaxf(Bvv, R);
            cand[b][2 * jj + 1] = Ft - R;
        }
    } else {
        float vv[16], sfx[16];
#pragma unroll
        for (int j = 0; j < 16; ++j) {
            const int i = ib + 16 * h + j;
            vv[j] = (i < t) ? FT[i * BB + b] : NEG_INF;
        }
        sfx[15] = vv[15];
#pragma unroll
        for (int j = 14; j >= 0; --j) sfx[j] = fmaxf(vv[j], sfx[j + 1]);
        Tot[h][b] = sfx[0];
        __syncthreads();
        const float carry = (h == 0) ? Tot[1][b] : NEG_INF;
        const float ub = u[t * BB + b];
#pragma unroll
        for (int j = 0; j < 16; ++j) {
            const int jj = 16 * h + j;
            const int i = ib + jj;
            const float R = fmaxf(sfx[j], carry);
            const float Bvv = BvT[i * BB + b];
            cand[b][2 * jj]     = Ft - fmaxf(Bvv, R);
            cand[b][2 * jj + 1] = (i == t) ? ub : (Ft - R);
        }
    }
    __syncthreads();

    {
        const int s = tid & 63, g = tid >> 6;
        float mx = NEG_INF;
        const int b0 = g * 32;
#pragma unroll 8
        for (int bb = b0; bb < b0 + 32; ++bb) mx = fmaxf(mx, cand[bb][s]);
        red[g][s] = mx;
    }
    __syncthreads();
    if (tid < 64) {
        const float r = fmaxf(fmaxf(red[0][tid], red[1][tid]),
                              fmaxf(red[2][tid], red[3][tid]));
        const int s_glob = 64 * ci + tid;
        if (s_glob < 2 * t + 2) m[(size_t)t * SS + s_glob] = r;
    }
}

// ============================================================
// phaseC_mfma — Round-9: R8 structure, NO waves-per-EU cap.
//   R8 proved: LDS diet + split grid -> Occupancy 20->51%, but
//   __launch_bounds__(256,5) clamped VGPR to 48 -> 875 MB scratch
//   spill traffic -> 251 us.  Natural allocation (~88-100) fits
//   5 waves/SIMD (5*100=500<=512) WITHOUT any cap.
//   Everything else identical to R8: 28.2 KB LDS (global-prefetch
//   aux), 12-block/b split grid + atomic epilogue, pitch-72,
//   incremental range-max, 1-deep prefetch, setprio.
// ============================================================
#define PWH 72                 // row pitch in halfwords (16B-aligned rows)
#define PWW 36                 // row pitch in words
#define VTO 2304               // Ws = 64*36 words
#define TPO 6912               // Vt ends at 2304+4608=6912
#define FT0O 6976
#define SCMO 7040
// total 7056 words = 28224 B -> 5 blocks/CU by LDS

__global__ __launch_bounds__(256) void phaseC_mfma(
    const float* __restrict__ F, const float* __restrict__ Bvg,
    const float* __restrict__ d2T, const float* __restrict__ CSb,
    const float* __restrict__ CMT, const float* __restrict__ m,
    const float* __restrict__ v1, const float* __restrict__ v2,
    float* __restrict__ out)
{
    const int b  = blockIdx.x & (BB - 1);
    const int wk = blockIdx.x >> 7;

    // work table: wk 0..5 : 8-chunk blocks (7,0)(7,8)(6,0)(5,0)(4,0)(3,0)
    //             wk 6..11: (6,8,6)(2,0,6)(5,8,4)(1,0,4)(4,8,2)(0,0,2)
    int tt, ck0, nck;
    if (wk < 6) {
        nck = 8;
        ck0 = (wk == 1) ? 8 : 0;
        tt  = (wk <= 1) ? 7 : 8 - wk;
    } else {
        const int j = wk - 6;
        nck = 6 - 2 * (j >> 1);
        if (j & 1) { tt = 2 - (j >> 1); ck0 = 0; }
        else       { tt = 6 - (j >> 1); ck0 = 8; }
    }
    const int t0 = tt * 64;
    const int t0c = t0 >> 5;               // # strictly-below chunks
    const int ckEnd = ck0 + nck;
    const bool splitTile = (tt >= 4);      // 2 writers -> atomicAdd

    const int tid = threadIdx.x;

    __shared__ float sh[7056];

    const int lane = tid & 63, w = tid >> 6;
    const int wr = w >> 1, wc = w & 1;            // 2x2 wave grid
    const int n = lane & 15;
    const int kq = (lane >> 4) * 8;
    const int il = tid & 31, g = tid >> 5;        // W staging
    const int veb = tid & 7;                      // V staging: e quad
    const int vip = ((tid >> 3) & 7) + 8 * wc;    // i-pair 0..15
    const int veh = wr * 64;                      // e half

    // ---------- pipeline registers ----------
    float4 pv[8];
    float2 pmv[8];
    float pAi, pBi, pAux;   // F[i-1], Bv[i], (below? CSb[i] : d2T[i])

    auto prefetch = [&](int ck) {
        const int i = 32 * ck + il;
#pragma unroll
        for (int r8 = 0; r8 < 8; ++r8) {
            const int t = t0 + 8 * g + r8;
            pmv[r8] = *(const float2*)&m[(size_t)t * SS + 2 * i];
        }
        pAi  = F  [b * TT + ((i > 0) ? i - 1 : 0)];
        pBi  = Bvg[b * TT + i];
        pAux = (32 * ck < t0) ? CSb[b * TT + i] : d2T[b * TT + i];
        const int i0 = 32 * ck + 2 * vip, i1 = i0 + 1;
        const float* p10 = v1 + ((size_t)i0 * BB + b) * EE;
        const float* p11 = v1 + ((size_t)i1 * BB + b) * EE;
        const float* p20 = v2 + ((size_t)i0 * BB + b) * EE;
        const float* p21 = v2 + ((size_t)i1 * BB + b) * EE;
#pragma unroll
        for (int c = 0; c < 2; ++c) {
            const int e0 = 4 * veb + 32 * c + veh;
            pv[4 * c + 0] = *(const float4*)&p10[e0];
            pv[4 * c + 1] = *(const float4*)&p11[e0];
            pv[4 * c + 2] = *(const float4*)&p20[e0];
            pv[4 * c + 3] = *(const float4*)&p21[e0];
        }
    };

    // ---------- prologue: FT0 + TP (wave 0), SCM (wave 1) ----------
    if (tid < 64) {
        float xi = F[b * TT + t0 + tid];
        sh[FT0O + tid] = xi;
        float sc = xi;
#pragma unroll
        for (int off = 1; off < 64; off <<= 1) {
            const float y = __shfl_up(sc, off);
            if (tid >= off) sc = fmaxf(sc, y);
        }
        const float ex = __shfl_up(sc, 1);
        sh[TPO + tid] = (tid == 0) ? NEG_INF : ex;
    } else if (tid < 128) {
        const int c = tid - 64;
        float cm = (c < t0c) ? CMT[c * BB + b] : NEG_INF;
#pragma unroll
        for (int off = 1; off < 16; off <<= 1) {
            const float y = __shfl_down(cm, off);
            cm = fmaxf(cm, (c + off < 16) ? y : NEG_INF);
        }
        if (c < 16) sh[SCMO + c] = cm;
    }

    prefetch(ck0);          // hide chunk-0 loads under prologue/barrier

    __syncthreads();

    float Freg2[8];
#pragma unroll
    for (int j = 0; j < 8; ++j) Freg2[j] = sh[FT0O + 8 * g + j];
    const float qstart = sh[TPO + 8 * g];

    floatx4 acc[2][4];
#pragma unroll
    for (int r = 0; r < 2; ++r)
#pragma unroll
        for (int j = 0; j < 4; ++j) acc[r][j] = (floatx4)0.f;

    for (int ck = ck0; ck < ckEnd; ++ck) {
        const int ib = 32 * ck;
        const int i = ib + il;
        const bool below = (ib < t0);          // block-uniform per chunk

        // ---- pack V fp16 first (pv dies -> lower reg peak) ----
        uint2 vreg[8];
#pragma unroll
        for (int c = 0; c < 2; ++c) {
            const float4 xa = pv[4 * c + 0], xb = pv[4 * c + 1];
            const float4 ya = pv[4 * c + 2], yb = pv[4 * c + 3];
            vreg[4 * c + 0] = make_uint2(pkh(xa.x, ya.x), pkh(xb.x, yb.x));
            vreg[4 * c + 1] = make_uint2(pkh(xa.y, ya.y), pkh(xb.y, yb.y));
            vreg[4 * c + 2] = make_uint2(pkh(xa.z, ya.z), pkh(xb.z, yb.z));
            vreg[4 * c + 3] = make_uint2(pkh(xa.w, ya.w), pkh(xb.w, yb.w));
        }

        // ---- W closed form + min(m) -> registers ----
        unsigned int wreg[8];
        {
            const float Ai = (i > 0) ? pAi : 0.f;
            const float Bi = pBi;
            const int li = i - t0;
            float q, S0i = 0.f;
            if (below) {
                S0i = fmaxf(pAux, sh[SCMO + ck + 1]);
                q = qstart;
            } else {
                q = NEG_INF;
                for (int k = li; k < 8 * g; ++k)
                    q = fmaxf(q, sh[FT0O + k]);
            }
#pragma unroll
            for (int r8 = 0; r8 < 8; ++r8) {
                const int t_l = 8 * g + r8;
                const float2 mv = pmv[r8];
                float w0 = 0.f, w1 = 0.f;
                if (below) {
                    const float R = fmaxf(S0i, q);
                    const float a0 = fmaxf(Ai, R) - fmaxf(Bi, R);
                    const float a1 = fmaxf(Bi - R, 0.f);
                    w0 = fminf(a0, mv.x);
                    w1 = fminf(a1, mv.y);
                    q = fmaxf(q, Freg2[r8]);
                } else {
                    if (li <= t_l) {
                        const float R = q;
                        const float a0 = fmaxf(Ai, R) - fmaxf(Bi, R);
                        const float a1 = (li == t_l) ? pAux
                                                     : fmaxf(Bi - R, 0.f);
                        w0 = fminf(a0, mv.x);
                        w1 = fminf(a1, mv.y);
                    }
                    q = fmaxf(q, (t_l >= li) ? Freg2[r8] : NEG_INF);
                }
                wreg[r8] = pkh(w0, w1);
            }
        }

        __syncthreads();                 // MFMA(prev) done reading LDS

        // ---- raw LDS writes only between the barriers ----
#pragma unroll
        for (int r8 = 0; r8 < 8; ++r8)
            ((unsigned int*)sh)[(8 * g + r8) * PWW + il] = wreg[r8];
        {
            unsigned int* vt = (unsigned int*)sh + VTO;
            const int dw = 2 * vip;
#pragma unroll
            for (int c = 0; c < 2; ++c) {
                const int e0 = 4 * veb + 32 * c + veh;
                *(uint2*)&vt[(e0 + 0) * PWW + dw] = vreg[4 * c + 0];
                *(uint2*)&vt[(e0 + 1) * PWW + dw] = vreg[4 * c + 1];
                *(uint2*)&vt[(e0 + 2) * PWW + dw] = vreg[4 * c + 2];
                *(uint2*)&vt[(e0 + 3) * PWW + dw] = vreg[4 * c + 3];
            }
        }

        __syncthreads();                 // staging visible

        // ---- issue NEXT chunk's global loads; latency under MFMA
        if (ck + 1 < ckEnd) prefetch(ck + 1);

        // ---- MFMA: 2 k-steps x (2 t-rows x 4 e-tiles) per wave ----
        __builtin_amdgcn_s_setprio(1);
        {
            const _Float16* WsH = (const _Float16*)sh;
            const _Float16* VtH = (const _Float16*)(sh + VTO);
#pragma unroll
            for (int k2 = 0; k2 < 64; k2 += 32) {
                const half8 av0 = *(const half8*)&WsH[(32 * wr + n) * PWH + kq + k2];
                const half8 av1 = *(const half8*)&WsH[(32 * wr + 16 + n) * PWH + kq + k2];
#pragma unroll
                for (int j = 0; j < 4; ++j) {
                    const half8 bv = *(const half8*)&VtH[(64 * wc + 16 * j + n) * PWH + kq + k2];
                    acc[0][j] = __builtin_amdgcn_mfma_f32_16x16x32_f16(av0, bv, acc[0][j], 0, 0, 0);
                    acc[1][j] = __builtin_amdgcn_mfma_f32_16x16x32_f16(av1, bv, acc[1][j], 0, 0, 0);
                }
            }
        }
        __builtin_amdgcn_s_setprio(0);
    }

    // ---- epilogue: store (single writer) or atomicAdd (split) ----
    {
        const int q = lane >> 4;
#pragma unroll
        for (int r = 0; r < 2; ++r) {
#pragma unroll
            for (int j = 0; j < 4; ++j) {
#pragma unroll
                for (int reg = 0; reg < 4; ++reg) {
                    const int t = t0 + 32 * wr + 16 * r + 4 * q + reg;
                    const int col = 64 * wc + 16 * j + n;
                    float* dst = &out[((size_t)t * BB + b) * EE + col];
                    if (splitTile) atomicAdd(dst, acc[r][j][reg]);
                    else           *dst = acc[r][j][reg];
                }
            }
        }
    }
}

// ============================================================
extern "C" void kernel_launch(void* const* d_in, const int* in_sizes, int n_in,
                              void* d_out, int out_size, void* d_ws, size_t ws_size,
                              hipStream_t stream) {
    const float* v1 = (const float*)d_in[0];
    const float* v2 = (const float*)d_in[1];
    const float* d1 = (const float*)d_in[2];
    const float* d2 = (const float*)d_in[3];
    const float* u  = (const float*)d_in[4];
    float* out = (float*)d_out;

    char* ws = (char*)d_ws;
    float* m   = (float*)ws;                                   // 2 MB
    float* F   = m   + (size_t)TT * SS;
    float* Bvp = F   + (size_t)BB * TT;
    float* d2T = Bvp + (size_t)BB * TT;
    float* FT  = d2T + (size_t)BB * TT;
    float* BvT = FT  + (size_t)BB * TT;
    float* CST = BvT + (size_t)BB * TT;
    float* HT  = CST + (size_t)BB * TT;
    float* CMT = HT  + (size_t)BB * TT;                        // 16*128
    float* CSb = CMT + (size_t)16 * BB;

    // zero the atomic-accumulated region (t >= 256) of out
    hipMemsetAsync(out + (size_t)256 * BB * EE, 0,
                   (size_t)256 * BB * EE * sizeof(float), stream);

    prefixF<<<dim3(BB), dim3(64), 0, stream>>>(d1, d2, u, F, Bvp, d2T, FT,
                                               BvT, CST, CMT, HT, CSb);
    calcM2 <<<dim3(16, TT), dim3(256), 0, stream>>>(FT, BvT, CST, CMT, HT, u, m);
    phaseC_mfma<<<dim3(12 * BB), dim3(256), 0, stream>>>(F, Bvp, d2T, CSb, CMT,
                                                         m, v1, v2, out);
}

// Round 11
// 186.291 us; speedup vs baseline: 2.0618x; 1.1083x over previous
//
#include <hip/hip_runtime.h>
#include <cstdint>
#include <cstddef>

#define TT 512
#define BB 128
#define EE 128
#define SS 1024
#define NEG_INF (-1e30f)

typedef _Float16 half8 __attribute__((ext_vector_type(8)));
typedef float floatx4 __attribute__((ext_vector_type(4)));

// ---------- fp16 helpers ----------
__device__ __forceinline__ unsigned int pkh(float x, float y) {
    _Float16 hx = (_Float16)x, hy = (_Float16)y;
    unsigned short bx, by;
    __builtin_memcpy(&bx, &hx, 2); __builtin_memcpy(&by, &hy, 2);
    return (unsigned int)bx | ((unsigned int)by << 16);
}

// ============================================================
// prefixF: per-b prefix sums + range-max precompute. (R9 version)
// ============================================================
__global__ __launch_bounds__(64) void prefixF(
    const float* __restrict__ d1, const float* __restrict__ d2,
    const float* __restrict__ u,
    float* __restrict__ F, float* __restrict__ Bv,
    float* __restrict__ d2T, float* __restrict__ FT,
    float* __restrict__ BvT, float* __restrict__ CST,
    float* __restrict__ CMT, float* __restrict__ HT,
    float* __restrict__ CSb)
{
    const int b = blockIdx.x;
    const int lane = threadIdx.x;
    const int t0 = lane * 8;

    float l1[8], l2[8], g[8];
#pragma unroll
    for (int j = 0; j < 8; ++j) {
        const int t = t0 + j;
        l1[j] = d1[t * BB + b];
        l2[j] = d2[t * BB + b];
        g[j] = u[t * BB + b] - l1[j] - l2[j];
    }
    float p[8], s = 0.f;
#pragma unroll
    for (int j = 0; j < 8; ++j) { s += g[j]; p[j] = s; }

    float v = s;
#pragma unroll
    for (int off = 1; off < 64; off <<= 1) {
        float o = __shfl_up(v, off);
        if (lane >= off) v += o;
    }
    const float excl = v - s;

    float Fv[8];
#pragma unroll
    for (int j = 0; j < 8; ++j) Fv[j] = excl + p[j];

#pragma unroll
    for (int j = 0; j < 8; ++j) {
        const int t = t0 + j;
        const float Fm1 = (j > 0) ? Fv[j - 1] : excl;
        const float Bvv = Fm1 - l1[j];
        F  [b * TT + t] = Fv[j];
        Bv [b * TT + t] = Bvv;
        d2T[b * TT + t] = l2[j];
        FT [t * BB + b] = Fv[j];
        BvT[t * BB + b] = Bvv;
    }

    // ---- range-max structures (chunk = 32 t = 4 lanes) ----
    float pm[8], sm[8];
    pm[0] = Fv[0];
#pragma unroll
    for (int j = 1; j < 8; ++j) pm[j] = fmaxf(pm[j - 1], Fv[j]);
    sm[7] = Fv[7];
#pragma unroll
    for (int j = 6; j >= 0; --j) sm[j] = fmaxf(sm[j + 1], Fv[j]);

    float pcar = NEG_INF, scar = NEG_INF;
#pragma unroll
    for (int off = 1; off <= 3; ++off) {
        float xu = __shfl_up(pm[7], off);
        if ((lane & 3) >= off) pcar = fmaxf(pcar, xu);
        float xd = __shfl_down(sm[0], off);
        if ((lane & 3) + off <= 3) scar = fmaxf(scar, xd);
    }

#pragma unroll
    for (int j = 0; j < 8; ++j) {
        const int t = t0 + j;
        const float Hv  = fmaxf(pcar, (j > 0) ? pm[j - 1] : NEG_INF);
        const float CSv = fmaxf(sm[j], scar);
        HT [t * BB + b] = Hv;
        CST[t * BB + b] = CSv;
        CSb[b * TT + t] = CSv;          // b-major for phaseC
    }
    if ((lane & 3) == 0)
        CMT[(lane >> 2) * BB + b] = fmaxf(sm[0], scar);
}

// ============================================================
// calcM2 (original — unchanged, ~11 us)
// ============================================================
__global__ __launch_bounds__(256) void calcM2(
    const float* __restrict__ FT, const float* __restrict__ BvT,
    const float* __restrict__ CST, const float* __restrict__ CMT,
    const float* __restrict__ HT, const float* __restrict__ u,
    float* __restrict__ m)
{
    const int t = (int)blockIdx.y;
    const int ci = (int)blockIdx.x;
    const int ct = t >> 5;
    if (ci > ct) return;

    const int tid = threadIdx.x;
    const int b = tid & 127, h = tid >> 7;
    const int ib = 32 * ci;

    __shared__ float cand[BB][66];
    __shared__ float Tot[2][BB];
    __shared__ float red[4][64];

    const float Ft = FT[t * BB + b];

    if (ci < ct) {
        float K = HT[t * BB + b];
        for (int c = ci + 1; c < ct; ++c) K = fmaxf(K, CMT[c * BB + b]);
#pragma unroll
        for (int j = 0; j < 16; ++j) {
            const int jj = 16 * h + j;
            const int i = ib + jj;
            const float R = fmaxf(CST[i * BB + b], K);
            const float Bvv = BvT[i * BB + b];
            cand[b][2 * jj]     = Ft - fmaxf(Bvv, R);
            cand[b][2 * jj + 1] = Ft - R;
        }
    } else {
        float vv[16], sfx[16];
#pragma unroll
        for (int j = 0; j < 16; ++j) {
            const int i = ib + 16 * h + j;
            vv[j] = (i < t) ? FT[i * BB + b] : NEG_INF;
        }
        sfx[15] = vv[15];
#pragma unroll
        for (int j = 14; j >= 0; --j) sfx[j] = fmaxf(vv[j], sfx[j + 1]);
        Tot[h][b] = sfx[0];
        __syncthreads();
        const float carry = (h == 0) ? Tot[1][b] : NEG_INF;
        const float ub = u[t * BB + b];
#pragma unroll
        for (int j = 0; j < 16; ++j) {
            const int jj = 16 * h + j;
            const int i = ib + jj;
            const float R = fmaxf(sfx[j], carry);
            const float Bvv = BvT[i * BB + b];
            cand[b][2 * jj]     = Ft - fmaxf(Bvv, R);
            cand[b][2 * jj + 1] = (i == t) ? ub : (Ft - R);
        }
    }
    __syncthreads();

    {
        const int s = tid & 63, g = tid >> 6;
        float mx = NEG_INF;
        const int b0 = g * 32;
#pragma unroll 8
        for (int bb = b0; bb < b0 + 32; ++bb) mx = fmaxf(mx, cand[bb][s]);
        red[g][s] = mx;
    }
    __syncthreads();
    if (tid < 64) {
        const float r = fmaxf(fmaxf(red[0][tid], red[1][tid]),
                              fmaxf(red[2][tid], red[3][tid]));
        const int s_glob = 64 * ci + tid;
        if (s_glob < 2 * t + 2) m[(size_t)t * SS + s_glob] = r;
    }
}

// ============================================================
// phaseC_mfma — Round-11: R10 double-buffer structure with the
// Vt base-offset BUG FIXED: Vt starts at word VTW=2048 inside the
// buffer -> halfword 4096 (= VTH).  R10 used 8192 (2*VTW*2) which
// read past Vt / out of the LDS allocation -> NaN.
//   Schedule (unchanged from R10):
//     iter ck:  MFMA(ck) <- buf[ck&1]
//               stage(ck+1) -> buf[(ck+1)&1]  (overlaps MFMA)
//               prefetch(ck+2)
//               ONE __syncthreads()
//   LDS: pitch 64 halfwords, XOR swizzle (word col ^= (row&7)<<2;
//   read halfword col ^= (n&7)<<3).  49.7 KB -> 3 blocks/CU.
// ============================================================
#define BUFW 6144              // words per buffer (Ws 2048 + Vt 4096)
#define BUFH 12288             // halfwords per buffer
#define VTW  2048              // Vt word offset inside buffer
#define VTH  4096              // Vt halfword offset inside buffer (FIX)
#define FT0O 12288             // word offsets of tables
#define TPO  12352
#define SCMO 12416
// total 12432 floats = 49728 B -> 3 blocks/CU

__global__ __launch_bounds__(256) void phaseC_mfma(
    const float* __restrict__ F, const float* __restrict__ Bvg,
    const float* __restrict__ d2T, const float* __restrict__ CSb,
    const float* __restrict__ CMT, const float* __restrict__ m,
    const float* __restrict__ v1, const float* __restrict__ v2,
    float* __restrict__ out)
{
    const int b  = blockIdx.x & (BB - 1);
    const int tt = 7 - (blockIdx.x >> 7);      // heavy blocks first
    const int t0 = tt * 64;
    const int t0c = t0 >> 5;                   // # strictly-below chunks
    const int nchunks = 2 * tt + 2;

    const int tid = threadIdx.x;

    __shared__ float sh[12432];

    const int lane = tid & 63, w = tid >> 6;
    const int wr = w >> 1, wc = w & 1;            // 2x2 wave grid
    const int n = lane & 15;
    const int kq = (lane >> 4) * 8;
    const int il = tid & 31, g = tid >> 5;        // W staging
    const int veb = tid & 7;                      // V staging: e quad
    const int vip = ((tid >> 3) & 7) + 8 * wc;    // i-pair 0..15
    const int veh = wr * 64;                      // e half

    // ---------- pipeline registers (single set, consume-then-refill)
    float4 pv[8];
    float2 pmv[8];
    float pAi, pBi, pAux;

    auto prefetch = [&](int ck) {
        const int i = 32 * ck + il;
#pragma unroll
        for (int r8 = 0; r8 < 8; ++r8) {
            const int t = t0 + 8 * g + r8;
            pmv[r8] = *(const float2*)&m[(size_t)t * SS + 2 * i];
        }
        pAi  = F  [b * TT + ((i > 0) ? i - 1 : 0)];
        pBi  = Bvg[b * TT + i];
        pAux = (32 * ck < t0) ? CSb[b * TT + i] : d2T[b * TT + i];
        const int i0 = 32 * ck + 2 * vip, i1 = i0 + 1;
        const float* p10 = v1 + ((size_t)i0 * BB + b) * EE;
        const float* p11 = v1 + ((size_t)i1 * BB + b) * EE;
        const float* p20 = v2 + ((size_t)i0 * BB + b) * EE;
        const float* p21 = v2 + ((size_t)i1 * BB + b) * EE;
#pragma unroll
        for (int c = 0; c < 2; ++c) {
            const int e0 = 4 * veb + 32 * c + veh;
            pv[4 * c + 0] = *(const float4*)&p10[e0];
            pv[4 * c + 1] = *(const float4*)&p11[e0];
            pv[4 * c + 2] = *(const float4*)&p20[e0];
            pv[4 * c + 3] = *(const float4*)&p21[e0];
        }
    };

    float Freg2[8];
    float qstart;

    // stage chunk cks: regs -> wreg/vreg -> buf[cks&1] (swizzled)
    auto stage = [&](int cks) {
        const int iS = 32 * cks + il;
        const bool belowS = (32 * cks < t0);
        const int p = cks & 1;

        unsigned int wreg[8];
        {
            const float Ai = (iS > 0) ? pAi : 0.f;
            const float Bi = pBi;
            const int li = iS - t0;
            float q, S0i = 0.f;
            if (belowS) {
                S0i = fmaxf(pAux, sh[SCMO + cks + 1]);
                q = qstart;
            } else {
                q = NEG_INF;
                for (int k = li; k < 8 * g; ++k)
                    q = fmaxf(q, sh[FT0O + k]);
            }
#pragma unroll
            for (int r8 = 0; r8 < 8; ++r8) {
                const int t_l = 8 * g + r8;
                const float2 mv = pmv[r8];
                float w0 = 0.f, w1 = 0.f;
                if (belowS) {
                    const float R = fmaxf(S0i, q);
                    const float a0 = fmaxf(Ai, R) - fmaxf(Bi, R);
                    const float a1 = fmaxf(Bi - R, 0.f);
                    w0 = fminf(a0, mv.x);
                    w1 = fminf(a1, mv.y);
                    q = fmaxf(q, Freg2[r8]);
                } else {
                    if (li <= t_l) {
                        const float R = q;
                        const float a0 = fmaxf(Ai, R) - fmaxf(Bi, R);
                        const float a1 = (li == t_l) ? pAux
                                                     : fmaxf(Bi - R, 0.f);
                        w0 = fminf(a0, mv.x);
                        w1 = fminf(a1, mv.y);
                    }
                    q = fmaxf(q, (t_l >= li) ? Freg2[r8] : NEG_INF);
                }
                wreg[r8] = pkh(w0, w1);
            }
        }

        uint2 vreg[8];
#pragma unroll
        for (int c = 0; c < 2; ++c) {
            const float4 xa = pv[4 * c + 0], xb = pv[4 * c + 1];
            const float4 ya = pv[4 * c + 2], yb = pv[4 * c + 3];
            vreg[4 * c + 0] = make_uint2(pkh(xa.x, ya.x), pkh(xb.x, yb.x));
            vreg[4 * c + 1] = make_uint2(pkh(xa.y, ya.y), pkh(xb.y, yb.y));
            vreg[4 * c + 2] = make_uint2(pkh(xa.z, ya.z), pkh(xb.z, yb.z));
            vreg[4 * c + 3] = make_uint2(pkh(xa.w, ya.w), pkh(xb.w, yb.w));
        }

        // Ws writes: word = p*BUFW + row*32 + (il ^ ((row&7)<<2))
#pragma unroll
        for (int r8 = 0; r8 < 8; ++r8)
            ((unsigned int*)sh)[p * BUFW + (8 * g + r8) * 32 + (il ^ (r8 << 2))]
                = wreg[r8];
        // Vt writes: word pair at p*BUFW + VTW + e*32 + ((2vip)^((e&7)<<2))
        {
            unsigned int* vt = (unsigned int*)sh + p * BUFW + VTW;
#pragma unroll
            for (int c = 0; c < 2; ++c) {
                const int e0 = 4 * veb + 32 * c + veh;
#pragma unroll
                for (int k = 0; k < 4; ++k) {
                    const int e = e0 + k;
                    *(uint2*)&vt[e * 32 + ((2 * vip) ^ ((e & 7) << 2))]
                        = vreg[4 * c + k];
                }
            }
        }
    };

    floatx4 acc[2][4];
#pragma unroll
    for (int r = 0; r < 2; ++r)
#pragma unroll
        for (int j = 0; j < 4; ++j) acc[r][j] = (floatx4)0.f;

    auto mfma_step = [&](int ck) {
        const int p = ck & 1;
        const _Float16* base = (const _Float16*)sh + p * BUFH;
        const int xsw = (n & 7) << 3;
        __builtin_amdgcn_s_setprio(1);
#pragma unroll
        for (int k2 = 0; k2 < 64; k2 += 32) {
            const int colr = (kq + k2) ^ xsw;
            const half8 av0 = *(const half8*)&base[(32 * wr + n) * 64 + colr];
            const half8 av1 = *(const half8*)&base[(32 * wr + 16 + n) * 64 + colr];
#pragma unroll
            for (int j = 0; j < 4; ++j) {
                const half8 bv = *(const half8*)&base[VTH +
                                     (64 * wc + 16 * j + n) * 64 + colr];
                acc[0][j] = __builtin_amdgcn_mfma_f32_16x16x32_f16(av0, bv, acc[0][j], 0, 0, 0);
                acc[1][j] = __builtin_amdgcn_mfma_f32_16x16x32_f16(av1, bv, acc[1][j], 0, 0, 0);
            }
        }
        __builtin_amdgcn_s_setprio(0);
    };

    // ---------- prologue ----------
    prefetch(0);                       // chunk-0 loads issue early

    // tables: FT0 + TP (wave 0), SCM (wave 1)
    if (tid < 64) {
        float xi = F[b * TT + t0 + tid];
        sh[FT0O + tid] = xi;
        float sc = xi;
#pragma unroll
        for (int off = 1; off < 64; off <<= 1) {
            const float y = __shfl_up(sc, off);
            if (tid >= off) sc = fmaxf(sc, y);
        }
        const float ex = __shfl_up(sc, 1);
        sh[TPO + tid] = (tid == 0) ? NEG_INF : ex;
    } else if (tid < 128) {
        const int c = tid - 64;
        float cm = (c < t0c) ? CMT[c * BB + b] : NEG_INF;
#pragma unroll
        for (int off = 1; off < 16; off <<= 1) {
            const float y = __shfl_down(cm, off);
            cm = fmaxf(cm, (c + off < 16) ? y : NEG_INF);
        }
        if (c < 16) sh[SCMO + c] = cm;
    }

    __syncthreads();                   // tables visible

#pragma unroll
    for (int j = 0; j < 8; ++j) Freg2[j] = sh[FT0O + 8 * g + j];
    qstart = sh[TPO + 8 * g];

    stage(0);                          // buf0 <- chunk 0
    if (1 < nchunks) prefetch(1);
    __syncthreads();                   // buf0 visible

    // ---------- main loop: 1 barrier per chunk ----------
    for (int ck = 0; ck < nchunks; ++ck) {
        mfma_step(ck);                 // reads buf[ck&1]
        if (ck + 1 < nchunks) {
            stage(ck + 1);             // writes buf[(ck+1)&1] (disjoint)
            if (ck + 2 < nchunks) prefetch(ck + 2);
        }
        __syncthreads();
    }

    // ---------- epilogue: plain stores ----------
    {
        const int q = lane >> 4;
#pragma unroll
        for (int r = 0; r < 2; ++r) {
#pragma unroll
            for (int j = 0; j < 4; ++j) {
#pragma unroll
                for (int reg = 0; reg < 4; ++reg) {
                    const int t = t0 + 32 * wr + 16 * r + 4 * q + reg;
                    const int col = 64 * wc + 16 * j + n;
                    out[((size_t)t * BB + b) * EE + col] = acc[r][j][reg];
                }
            }
        }
    }
}

// ============================================================
extern "C" void kernel_launch(void* const* d_in, const int* in_sizes, int n_in,
                              void* d_out, int out_size, void* d_ws, size_t ws_size,
                              hipStream_t stream) {
    const float* v1 = (const float*)d_in[0];
    const float* v2 = (const float*)d_in[1];
    const float* d1 = (const float*)d_in[2];
    const float* d2 = (const float*)d_in[3];
    const float* u  = (const float*)d_in[4];
    float* out = (float*)d_out;

    char* ws = (char*)d_ws;
    float* m   = (float*)ws;                                   // 2 MB
    float* F   = m   + (size_t)TT * SS;
    float* Bvp = F   + (size_t)BB * TT;
    float* d2T = Bvp + (size_t)BB * TT;
    float* FT  = d2T + (size_t)BB * TT;
    float* BvT = FT  + (size_t)BB * TT;
    float* CST = BvT + (size_t)BB * TT;
    float* HT  = CST + (size_t)BB * TT;
    float* CMT = HT  + (size_t)BB * TT;                        // 16*128
    float* CSb = CMT + (size_t)16 * BB;

    prefixF<<<dim3(BB), dim3(64), 0, stream>>>(d1, d2, u, F, Bvp, d2T, FT,
                                               BvT, CST, CMT, HT, CSb);
    calcM2 <<<dim3(16, TT), dim3(256), 0, stream>>>(FT, BvT, CST, CMT, HT, u, m);
    phaseC_mfma<<<dim3(8 * BB), dim3(256), 0, stream>>>(F, Bvp, d2T, CSb, CMT,
                                                        m, v1, v2, out);
}